// Round 3
// baseline (126.446 us; speedup 1.0000x reference)
//
#include <hip/hip_runtime.h>
#include <hip/hip_bf16.h>

// QuantumFeedForward, fully fused:
//   q[n,w]  = prod_{v in M_w} cos(theta_v)*cos(x[n,v])      (analytic circuit collapse)
//   out     = relu(q@W1^T+b1) @ W2^T + b2
// Single MFMA kernel generates the H=relu(...) tile on the fly (VALU, redundancy 2)
// while MFMA consumes the previous tile. No H round-trip through HBM.
// W2b is stored CHUNK-SWIZZLED in global (16B chunk c of row r at (c&~7)|((c&7)^(r&7)))
// so linear global_load_lds staging yields a conflict-free XOR-swizzled LDS tile.

typedef __attribute__((ext_vector_type(8))) short bf16x8;
typedef __attribute__((ext_vector_type(4))) float f32x4;
typedef __attribute__((ext_vector_type(8))) unsigned short us8;

#define NTOK  16384
#define EMBED 512
#define FFN   2048
#define NQ    10
#define BM    128
#define BN    256
#define BK    64
#define NT    (FFN / BK)   // 32

__device__ __forceinline__ unsigned short f2bf(float f) {
  union { float f; unsigned int u; } a; a.f = f;
  unsigned int r = a.u + 0x7FFFu + ((a.u >> 16) & 1u);   // RNE
  return (unsigned short)(r >> 16);
}

__device__ __forceinline__ void gload_lds16(const void* g, void* l) {
  __builtin_amdgcn_global_load_lds(
      (const __attribute__((address_space(1))) unsigned int*)g,
      (__attribute__((address_space(3))) unsigned int*)l, 16, 0, 0);
}

// ---------------- K0: W2 (512x2048 f32) -> bf16, chunk-swizzled ----------------
__global__ __launch_bounds__(256) void k_cvt_w2(const float* __restrict__ W2,
                                                unsigned short* __restrict__ W2b) {
  int gid = blockIdx.x * 256 + threadIdx.x;     // one 16B chunk (8 f32 -> 8 bf16)
  int idx = gid * 8;
  int row = idx >> 11;                          // /2048
  int c   = (idx >> 3) & 255;                   // chunk within row
  int sc  = (c & ~7) | ((c & 7) ^ (row & 7));   // swizzled chunk
  float4 v0 = *(const float4*)(W2 + idx);
  float4 v1 = *(const float4*)(W2 + idx + 4);
  us8 o;
  o[0] = f2bf(v0.x); o[1] = f2bf(v0.y); o[2] = f2bf(v0.z); o[3] = f2bf(v0.w);
  o[4] = f2bf(v1.x); o[5] = f2bf(v1.y); o[6] = f2bf(v1.z); o[7] = f2bf(v1.w);
  *(us8*)(W2b + (size_t)row * FFN + sc * 8) = o;
}

// ---------------- K0b: W1 (2048x10) -> W1t (10x2048) f32 ----------------
__global__ __launch_bounds__(256) void k_cvt_w1t(const float* __restrict__ W1,
                                                 float* __restrict__ W1t) {
  int idx = blockIdx.x * 256 + threadIdx.x;     // 0..20479; idx = w*2048+k
  int w = idx >> 11, k = idx & 2047;
  W1t[idx] = W1[k * NQ + w];
}

// ---------------- K1: fused H-gen + GEMM ----------------
__global__ __launch_bounds__(512) void k_fused(const float* __restrict__ x,
                                               const float* __restrict__ theta,
                                               const float* __restrict__ W1t,
                                               const float* __restrict__ b1,
                                               const unsigned short* __restrict__ W2b,
                                               const float* __restrict__ b2,
                                               float* __restrict__ out) {
  __shared__ float qs[BM][NQ];
  __shared__ short Ah[2][BM * BK];   // H tile, XOR-swizzled rows of 128B
  __shared__ short Bw[2][BN * BK];   // W2 tile, swizzle inherited from global layout

  // XCD-aware bijective swizzle: 256 blocks, 32 consecutive per XCD.
  int bid = blockIdx.x;
  int swz = (bid & 7) * 32 + (bid >> 3);
  const int m0 = (swz >> 1) * BM;
  const int n0 = (swz & 1) * BN;
  const int tid  = threadIdx.x;
  const int lane = tid & 63;
  const int wave = tid >> 6;               // 8 waves: 2 (M) x 4 (N)
  const int wr = wave >> 2, wc = wave & 3;

  // ---- prologue: q for this block's 128 tokens ----
  if (tid < BM) {
    const int masks[NQ] = {0x2AB,0x3FD,0x3FA,0x3F5,0x3EA,0x3D5,0x3AA,0x355,0x2AA,0x155};
    float z[NQ];
#pragma unroll
    for (int w = 0; w < NQ; ++w)
      z[w] = __builtin_cosf(x[(size_t)(m0 + tid) * EMBED + w]) * __builtin_cosf(theta[w]);
#pragma unroll
    for (int w = 0; w < NQ; ++w) {
      float p = 1.f;
#pragma unroll
      for (int v = 0; v < NQ; ++v)
        if ((masks[w] >> v) & 1) p *= z[v];
      qs[tid][w] = p;
    }
  }
  __syncthreads();

  // H-gen mapping: thread -> (k-octet, token pair); fixed tokens => q in regs.
  const int oct = tid & 7;          // 8 bf16 columns k = kt*64 + oct*8 ..+7
  const int grp = tid >> 3;         // 64 groups x 2 tokens
  const int t0 = grp * 2, t1 = t0 + 1;
  float q0r[NQ], q1r[NQ];
#pragma unroll
  for (int w = 0; w < NQ; ++w) { q0r[w] = qs[t0][w]; q1r[w] = qs[t1][w]; }

  f32x4 acc[4][4] = {};
  float h0[8], h1[8];

#define STAGE_W2(KT, B)                                                         \
  {                                                                             \
    _Pragma("unroll")                                                           \
    for (int p = 0; p < 4; ++p) {                                               \
      int ch = p * 512 + tid;                   /* 2048 chunks = 256r x 8s */   \
      int row = ch >> 3, slot = ch & 7;                                         \
      gload_lds16(&W2b[(size_t)(n0 + row) * FFN + (KT) * BK + slot * 8],        \
                  &Bw[B][ch * 8]);                                              \
    }                                                                           \
  }

#define HGEN(KT)                                                                \
  {                                                                             \
    const float* wp = W1t + (KT) * BK + oct * 8;                                \
    float4 ba = *(const float4*)(b1 + (KT) * BK + oct * 8);                     \
    float4 bb = *(const float4*)(b1 + (KT) * BK + oct * 8 + 4);                 \
    h0[0]=ba.x; h0[1]=ba.y; h0[2]=ba.z; h0[3]=ba.w;                             \
    h0[4]=bb.x; h0[5]=bb.y; h0[6]=bb.z; h0[7]=bb.w;                             \
    _Pragma("unroll")                                                           \
    for (int j = 0; j < 8; ++j) h1[j] = h0[j];                                  \
    _Pragma("unroll")                                                           \
    for (int w = 0; w < NQ; ++w) {                                              \
      float4 wa = *(const float4*)(wp + (size_t)w * FFN);                       \
      float4 wb = *(const float4*)(wp + (size_t)w * FFN + 4);                   \
      float a0 = q0r[w], a1 = q1r[w];                                           \
      h0[0] += a0*wa.x; h0[1] += a0*wa.y; h0[2] += a0*wa.z; h0[3] += a0*wa.w;   \
      h0[4] += a0*wb.x; h0[5] += a0*wb.y; h0[6] += a0*wb.z; h0[7] += a0*wb.w;   \
      h1[0] += a1*wa.x; h1[1] += a1*wa.y; h1[2] += a1*wa.z; h1[3] += a1*wa.w;   \
      h1[4] += a1*wb.x; h1[5] += a1*wb.y; h1[6] += a1*wb.z; h1[7] += a1*wb.w;   \
    }                                                                           \
  }

#define HWRITE(B)                                                               \
  {                                                                             \
    us8 o0, o1;                                                                 \
    _Pragma("unroll")                                                           \
    for (int j = 0; j < 8; ++j) {                                               \
      o0[j] = f2bf(fmaxf(h0[j], 0.f));                                          \
      o1[j] = f2bf(fmaxf(h1[j], 0.f));                                          \
    }                                                                           \
    *(us8*)&Ah[B][t0 * BK + (oct ^ (t0 & 7)) * 8] = o0;                         \
    *(us8*)&Ah[B][t1 * BK + (oct ^ (t1 & 7)) * 8] = o1;                         \
  }

  // ---- pipeline prologue: tile 0 ----
  STAGE_W2(0, 0);
  HGEN(0);
  HWRITE(0);
  __syncthreads();

  // ---- main loop: prefetch kt+1 (global W2 + VALU H) under MFMA of kt ----
  for (int kt = 0; kt < NT; ++kt) {
    const int cur = kt & 1;
    if (kt + 1 < NT) {
      STAGE_W2(kt + 1, cur ^ 1);
      HGEN(kt + 1);
    }
#pragma unroll
    for (int kk = 0; kk < 2; ++kk) {
      bf16x8 af[4], bg[4];
#pragma unroll
      for (int i = 0; i < 4; ++i) {
        int row = wr * 64 + i * 16 + (lane & 15);
        int slot = (kk * 4 + (lane >> 4)) ^ (row & 7);
        af[i] = *(const bf16x8*)&Ah[cur][row * BK + slot * 8];
      }
#pragma unroll
      for (int j = 0; j < 4; ++j) {
        int row = wc * 64 + j * 16 + (lane & 15);
        int slot = (kk * 4 + (lane >> 4)) ^ (row & 7);
        bg[j] = *(const bf16x8*)&Bw[cur][row * BK + slot * 8];
      }
      __builtin_amdgcn_s_setprio(1);
#pragma unroll
      for (int i = 0; i < 4; ++i)
#pragma unroll
        for (int j = 0; j < 4; ++j)
          acc[i][j] = __builtin_amdgcn_mfma_f32_16x16x32_bf16(af[i], bg[j], acc[i][j], 0, 0, 0);
      __builtin_amdgcn_s_setprio(0);
    }
    if (kt + 1 < NT) HWRITE(cur ^ 1);
    __syncthreads();   // one barrier per K-step; prefetch had full MFMA phase to land
  }

  // ---- epilogue: out = acc + b2 ----
#pragma unroll
  for (int i = 0; i < 4; ++i) {
    const int row = m0 + wr * 64 + i * 16 + (lane >> 4) * 4;
#pragma unroll
    for (int j = 0; j < 4; ++j) {
      const int col = n0 + wc * 64 + j * 16 + (lane & 15);
      const float bbv = b2[col];
#pragma unroll
      for (int r = 0; r < 4; ++r)
        out[(size_t)(row + r) * EMBED + col] = acc[i][j][r] + bbv;
    }
  }
#undef STAGE_W2
#undef HGEN
#undef HWRITE
}

extern "C" void kernel_launch(void* const* d_in, const int* in_sizes, int n_in,
                              void* d_out, int out_size, void* d_ws, size_t ws_size,
                              hipStream_t stream) {
  const float* x     = (const float*)d_in[0];
  const float* theta = (const float*)d_in[1];
  const float* W1    = (const float*)d_in[2];
  const float* b1    = (const float*)d_in[3];
  const float* W2    = (const float*)d_in[4];
  const float* b2    = (const float*)d_in[5];
  float* out = (float*)d_out;

  char* ws = (char*)d_ws;
  unsigned short* W2b = (unsigned short*)ws;                 // 2 MB bf16 swizzled
  float* W1t = (float*)(ws + (2u << 20));                    // 80 KB f32 transposed

  k_cvt_w2<<<(EMBED * FFN) / (256 * 8), 256, 0, stream>>>(W2, W2b);
  k_cvt_w1t<<<(NQ * FFN) / 256, 256, 0, stream>>>(W1, W1t);
  k_fused<<<(NTOK / BM) * (EMBED / BN), 512, 0, stream>>>(x, theta, W1t, b1, W2b, b2, out);
}

// Round 4
// 79.133 us; speedup vs baseline: 1.5979x; 1.5979x over previous
//
#include <hip/hip_runtime.h>
#include <hip/hip_bf16.h>

// QuantumFeedForward, fully fused:
//   q[n,w]  = prod_{v in M_w} cos(theta_v)*cos(x[n,v])      (analytic circuit collapse)
//   out     = relu(q@W1^T+b1) @ W2^T + b2
// One MFMA kernel generates each H k-tile on the fly (VALU) while MFMA consumes the
// previous tile. W1/b1 step-slices are LDS-staged at prefetch distance 2 so HGEN
// never touches global memory. W2b is CHUNK-SWIZZLED in global (chunk c of row r at
// (c&~7)|((c&7)^(r&7))) so linear global_load_lds yields a conflict-free LDS tile.

typedef __attribute__((ext_vector_type(8))) short bf16x8;
typedef __attribute__((ext_vector_type(4))) float f32x4;
typedef __attribute__((ext_vector_type(2))) float f32x2;
typedef __attribute__((ext_vector_type(8))) unsigned short us8;

#define NTOK  16384
#define EMBED 512
#define FFN   2048
#define NQ    10
#define BM    128
#define BN    256
#define BK    64
#define NT    (FFN / BK)   // 32

__device__ __forceinline__ unsigned short f2bf(float f) {
  union { float f; unsigned int u; } a; a.f = f;
  unsigned int r = a.u + 0x7FFFu + ((a.u >> 16) & 1u);   // RNE
  return (unsigned short)(r >> 16);
}

__device__ __forceinline__ void gload_lds16(const void* g, void* l) {
  __builtin_amdgcn_global_load_lds(
      (const __attribute__((address_space(1))) unsigned int*)g,
      (__attribute__((address_space(3))) unsigned int*)l, 16, 0, 0);
}

// ---------------- K0: W2 (512x2048 f32) -> bf16, chunk-swizzled ----------------
__global__ __launch_bounds__(256) void k_cvt_w2(const float* __restrict__ W2,
                                                unsigned short* __restrict__ W2b) {
  int gid = blockIdx.x * 256 + threadIdx.x;     // one 16B chunk (8 f32 -> 8 bf16)
  int idx = gid * 8;
  int row = idx >> 11;                          // /2048
  int c   = (idx >> 3) & 255;                   // chunk within row
  int sc  = (c & ~7) | ((c & 7) ^ (row & 7));   // swizzled chunk
  float4 v0 = *(const float4*)(W2 + idx);
  float4 v1 = *(const float4*)(W2 + idx + 4);
  us8 o;
  o[0] = f2bf(v0.x); o[1] = f2bf(v0.y); o[2] = f2bf(v0.z); o[3] = f2bf(v0.w);
  o[4] = f2bf(v1.x); o[5] = f2bf(v1.y); o[6] = f2bf(v1.z); o[7] = f2bf(v1.w);
  *(us8*)(W2b + (size_t)row * FFN + sc * 8) = o;
}

// ---------------- K0b: W1 (2048x10) -> W1t (10x2048) f32 ----------------
__global__ __launch_bounds__(256) void k_cvt_w1t(const float* __restrict__ W1,
                                                 float* __restrict__ W1t) {
  int idx = blockIdx.x * 256 + threadIdx.x;     // idx = w*2048+k
  int w = idx >> 11, k = idx & 2047;
  W1t[idx] = W1[k * NQ + w];
}

// ---------------- K1: fused H-gen + GEMM ----------------
__global__ __launch_bounds__(512) void k_fused(const float* __restrict__ x,
                                               const float* __restrict__ theta,
                                               const float* __restrict__ W1t,
                                               const float* __restrict__ b1,
                                               const unsigned short* __restrict__ W2b,
                                               const float* __restrict__ b2,
                                               float* __restrict__ out) {
  __shared__ float qs[BM][NQ];
  __shared__ short Ah[2][BM * BK];       // H tile, XOR-swizzled rows of 128B
  __shared__ short Bw[2][BN * BK];       // W2 tile, swizzle inherited from global
  __shared__ float W1s[2][NQ * BK];      // per-step W1 slice [w][64], dist-2 prefetch
  __shared__ float b1s[2][BK];

  // XCD-aware bijective swizzle: 256 blocks, 32 consecutive per XCD.
  int bid = blockIdx.x;
  int swz = (bid & 7) * 32 + (bid >> 3);
  const int m0 = (swz >> 1) * BM;
  const int n0 = (swz & 1) * BN;
  const int tid  = threadIdx.x;
  const int lane = tid & 63;
  const int wave = tid >> 6;             // 8 waves: 2 (M) x 4 (N)
  const int wr = wave >> 2, wc = wave & 3;

  // ---- q for this block's 128 tokens ----
  if (tid < BM) {
    const int masks[NQ] = {0x2AB,0x3FD,0x3FA,0x3F5,0x3EA,0x3D5,0x3AA,0x355,0x2AA,0x155};
    float z[NQ];
#pragma unroll
    for (int w = 0; w < NQ; ++w)
      z[w] = __builtin_cosf(x[(size_t)(m0 + tid) * EMBED + w]) * __builtin_cosf(theta[w]);
#pragma unroll
    for (int w = 0; w < NQ; ++w) {
      float p = 1.f;
#pragma unroll
      for (int v = 0; v < NQ; ++v)
        if ((masks[w] >> v) & 1) p *= z[v];
      qs[tid][w] = p;
    }
  }
  __syncthreads();

  // H-gen mapping: thread -> (k-octet, token pair).
  const int oct = tid & 7;               // 8 bf16 columns k = kt*64 + oct*8 ..+7
  const int grp = tid >> 3;              // 64 groups x 2 tokens
  const int t0 = grp * 2, t1 = t0 + 1;
  float q0r[NQ], q1r[NQ];
#pragma unroll
  for (int w = 0; w < NQ; ++w) { q0r[w] = qs[t0][w]; q1r[w] = qs[t1][w]; }

  f32x4 acc[4][4] = {};
  f32x2 h0p[4], h1p[4];

#define STAGE_W2(KT, B)                                                         \
  {                                                                             \
    _Pragma("unroll")                                                           \
    for (int p = 0; p < 4; ++p) {                                               \
      int ch = p * 512 + tid;                   /* 2048 chunks = 256r x 8s */   \
      int row = ch >> 3, slot = ch & 7;                                         \
      gload_lds16(&W2b[(size_t)(n0 + row) * FFN + (KT) * BK + slot * 8],        \
                  &Bw[B][ch * 8]);                                              \
    }                                                                           \
  }

  // W1 slice (10 rows x 64 f32) + b1 slice (64 f32) for step KT -> buffer B.
  // Wave w covers rows 4w..4w+3 (lane>>4), chunk lane&15; dest is linear in lane.
#define STAGE_W1(KT, B)                                                         \
  {                                                                             \
    if (wave < 3) {                                                             \
      int r = wave * 4 + (lane >> 4);                                           \
      if (r < NQ)                                                               \
        gload_lds16(&W1t[(size_t)r * FFN + (KT) * BK + (lane & 15) * 4],        \
                    &W1s[B][wave * 4 * BK]);                                    \
    } else if (wave == 3 && lane < 16) {                                        \
      gload_lds16(&b1[(KT) * BK + lane * 4], &b1s[B][0]);                       \
    }                                                                           \
  }

#define HGEN(B)                                                                 \
  {                                                                             \
    float4 ba = *(const float4*)&b1s[B][oct * 8];                               \
    float4 bb = *(const float4*)&b1s[B][oct * 8 + 4];                           \
    h0p[0] = (f32x2){ba.x, ba.y}; h0p[1] = (f32x2){ba.z, ba.w};                 \
    h0p[2] = (f32x2){bb.x, bb.y}; h0p[3] = (f32x2){bb.z, bb.w};                 \
    _Pragma("unroll")                                                           \
    for (int j = 0; j < 4; ++j) h1p[j] = h0p[j];                                \
    _Pragma("unroll")                                                           \
    for (int w = 0; w < NQ; ++w) {                                              \
      float4 wa = *(const float4*)&W1s[B][w * BK + oct * 8];                    \
      float4 wb = *(const float4*)&W1s[B][w * BK + oct * 8 + 4];                \
      f32x2 w0 = {wa.x, wa.y}, w1v = {wa.z, wa.w};                              \
      f32x2 w2v = {wb.x, wb.y}, w3 = {wb.z, wb.w};                              \
      f32x2 a0 = {q0r[w], q0r[w]}, a1 = {q1r[w], q1r[w]};                       \
      h0p[0] += a0 * w0; h0p[1] += a0 * w1v; h0p[2] += a0 * w2v; h0p[3] += a0 * w3; \
      h1p[0] += a1 * w0; h1p[1] += a1 * w1v; h1p[2] += a1 * w2v; h1p[3] += a1 * w3; \
    }                                                                           \
  }

#define HWRITE(B)                                                               \
  {                                                                             \
    us8 o0, o1;                                                                 \
    _Pragma("unroll")                                                           \
    for (int j = 0; j < 4; ++j) {                                               \
      o0[2*j]   = f2bf(fmaxf(h0p[j].x, 0.f));                                   \
      o0[2*j+1] = f2bf(fmaxf(h0p[j].y, 0.f));                                   \
      o1[2*j]   = f2bf(fmaxf(h1p[j].x, 0.f));                                   \
      o1[2*j+1] = f2bf(fmaxf(h1p[j].y, 0.f));                                   \
    }                                                                           \
    *(us8*)&Ah[B][t0 * BK + (oct ^ (t0 & 7)) * 8] = o0;                         \
    *(us8*)&Ah[B][t1 * BK + (oct ^ (t1 & 7)) * 8] = o1;                         \
  }

  // ---- pipeline prologue ----
  STAGE_W1(0, 0);
  STAGE_W1(1, 1);
  STAGE_W2(0, 0);
  __syncthreads();            // drains vmcnt: W1s/b1s[0,1] + Bw[0] ready
  HGEN(0);
  HWRITE(0);
  __syncthreads();            // Ah[0] ready

  // ---- main loop ----
  for (int kt = 0; kt < NT; ++kt) {
    const int cur = kt & 1, nxt = cur ^ 1;
    if (kt + 2 < NT) STAGE_W1(kt + 2, cur);   // slice kt in W1s[cur] was consumed last iter
    if (kt + 1 < NT) {
      STAGE_W2(kt + 1, nxt);
      HGEN(nxt);              // reads W1s[nxt]: staged iter kt-1, drained at its barrier
    }
#pragma unroll
    for (int kk = 0; kk < 2; ++kk) {
      bf16x8 af[4], bg[4];
#pragma unroll
      for (int i = 0; i < 4; ++i) {
        int row = wr * 64 + i * 16 + (lane & 15);
        int slot = (kk * 4 + (lane >> 4)) ^ (row & 7);
        af[i] = *(const bf16x8*)&Ah[cur][row * BK + slot * 8];
      }
#pragma unroll
      for (int j = 0; j < 4; ++j) {
        int row = wc * 64 + j * 16 + (lane & 15);
        int slot = (kk * 4 + (lane >> 4)) ^ (row & 7);
        bg[j] = *(const bf16x8*)&Bw[cur][row * BK + slot * 8];
      }
      __builtin_amdgcn_s_setprio(1);
#pragma unroll
      for (int i = 0; i < 4; ++i)
#pragma unroll
        for (int j = 0; j < 4; ++j)
          acc[i][j] = __builtin_amdgcn_mfma_f32_16x16x32_bf16(af[i], bg[j], acc[i][j], 0, 0, 0);
      __builtin_amdgcn_s_setprio(0);
    }
    if (kt + 1 < NT) HWRITE(nxt);
    __syncthreads();          // one barrier per K-step
  }

  // ---- epilogue: out = acc + b2 ----
#pragma unroll
  for (int i = 0; i < 4; ++i) {
    const int row = m0 + wr * 64 + i * 16 + (lane >> 4) * 4;
#pragma unroll
    for (int j = 0; j < 4; ++j) {
      const int col = n0 + wc * 64 + j * 16 + (lane & 15);
      const float bbv = b2[col];
#pragma unroll
      for (int r = 0; r < 4; ++r)
        out[(size_t)(row + r) * EMBED + col] = acc[i][j][r] + bbv;
    }
  }
#undef STAGE_W2
#undef STAGE_W1
#undef HGEN
#undef HWRITE
}

extern "C" void kernel_launch(void* const* d_in, const int* in_sizes, int n_in,
                              void* d_out, int out_size, void* d_ws, size_t ws_size,
                              hipStream_t stream) {
  const float* x     = (const float*)d_in[0];
  const float* theta = (const float*)d_in[1];
  const float* W1    = (const float*)d_in[2];
  const float* b1    = (const float*)d_in[3];
  const float* W2    = (const float*)d_in[4];
  const float* b2    = (const float*)d_in[5];
  float* out = (float*)d_out;

  char* ws = (char*)d_ws;
  unsigned short* W2b = (unsigned short*)ws;                 // 2 MB bf16 swizzled
  float* W1t = (float*)(ws + (2u << 20));                    // 80 KB f32 transposed

  k_cvt_w2<<<(EMBED * FFN) / (256 * 8), 256, 0, stream>>>(W2, W2b);
  k_cvt_w1t<<<(NQ * FFN) / 256, 256, 0, stream>>>(W1, W1t);
  k_fused<<<(NTOK / BM) * (EMBED / BN), 512, 0, stream>>>(x, theta, W1t, b1, W2b, b2, out);
}